// Round 5
// baseline (870.289 us; speedup 1.0000x reference)
//
#include <hip/hip_runtime.h>
#include <math.h>

#define B_ 4
#define C_ 64
#define M_ 8
#define H_ 224
#define W_ 224
#define N_ (H_*W_)        // 50176
#define CN_ (C_*N_)       // 3211264
#define MN_ (M_*N_)       // 401408
#define BCN_ (B_*CN_)
#define BMN_ (B_*MN_)

__device__ __forceinline__ float relu6f(float v){ return fminf(fmaxf(v,0.0f),6.0f); }
__device__ __forceinline__ float softplusf(float v){
  return v > 0.0f ? v + log1pf(expf(-v)) : log1pf(expf(v));
}

// ---------------------------------------------------------------------------
// K1: h = relu6(bn(conv1x1(x, fc1_w)))  AND  K = softplus(conv1x1(x,k_w)+k_b)
// Thread = 4 px x 8 oc. c-loop: chunks of 4, depth-2 register double-buffer
// (loads issued one full chunk ahead -> 4 KB/wave in flight, latency hidden).
// ---------------------------------------------------------------------------
__global__ __launch_bounds__(256, 3) void k_fc1k(const float* __restrict__ x,
                                                 const float* __restrict__ w,
                                                 const float* __restrict__ bn,
                                                 const float* __restrict__ kw,
                                                 const float* __restrict__ kb,
                                                 float* __restrict__ h,
                                                 float* __restrict__ Kq)
{
  __shared__ __align__(16) float wt[64*32];   // wt[c][o']  o' = oc - half*32
  __shared__ __align__(16) float kt[64*8];    // kt[c][m]
  const int tid  = threadIdx.x;
  const int b    = blockIdx.x / 392;
  const int rem  = blockIdx.x % 392;
  const int pg   = rem >> 1;
  const int half = rem & 1;

  for (int idx = tid; idx < 2048; idx += 256) {
    const int c = idx >> 5, o = idx & 31;
    wt[idx] = w[(half*32 + o)*64 + c];
  }
  for (int idx = tid; idx < 512; idx += 256) {
    const int c = idx >> 3, m = idx & 7;
    kt[idx] = kw[m*64 + c];
  }
  __syncthreads();

  const int lane = tid & 63, wave = tid >> 6;
  const int pix = pg*256 + 4*lane;
  const float* xb = x + (size_t)b*CN_ + pix;
  const int obl = wave*8;
  const int ob  = half*32 + obl;

  float4 acc[8];
  float4 ak0 = {0,0,0,0}, ak1 = {0,0,0,0};
  #pragma unroll
  for (int i = 0; i < 8; ++i) acc[i] = make_float4(0.f,0.f,0.f,0.f);

  float4 bx[2][4];
  #pragma unroll
  for (int j = 0; j < 4; ++j)
    bx[0][j] = *(const float4*)(xb + (size_t)j*N_);

  #pragma unroll
  for (int ck = 0; ck < 16; ++ck) {
    const int cur = ck & 1, nxt = cur ^ 1;
    if (ck < 15) {
      #pragma unroll
      for (int j = 0; j < 4; ++j)
        bx[nxt][j] = *(const float4*)(xb + (size_t)((ck+1)*4 + j)*N_);
    }
    #pragma unroll
    for (int j = 0; j < 4; ++j) {
      const int c = ck*4 + j;
      const float4 w0 = *(const float4*)&wt[c*32 + obl];
      const float4 w1 = *(const float4*)&wt[c*32 + obl + 4];
      const float2 k2 = *(const float2*)&kt[c*8 + wave*2];
      const float4 xv = bx[cur][j];
      const float wv[8] = {w0.x,w0.y,w0.z,w0.w,w1.x,w1.y,w1.z,w1.w};
      #pragma unroll
      for (int o = 0; o < 8; ++o) {
        acc[o].x = fmaf(wv[o], xv.x, acc[o].x);
        acc[o].y = fmaf(wv[o], xv.y, acc[o].y);
        acc[o].z = fmaf(wv[o], xv.z, acc[o].z);
        acc[o].w = fmaf(wv[o], xv.w, acc[o].w);
      }
      if (half == 0) {
        ak0.x = fmaf(k2.x, xv.x, ak0.x); ak0.y = fmaf(k2.x, xv.y, ak0.y);
        ak0.z = fmaf(k2.x, xv.z, ak0.z); ak0.w = fmaf(k2.x, xv.w, ak0.w);
        ak1.x = fmaf(k2.y, xv.x, ak1.x); ak1.y = fmaf(k2.y, xv.y, ak1.y);
        ak1.z = fmaf(k2.y, xv.z, ak1.z); ak1.w = fmaf(k2.y, xv.w, ak1.w);
      }
    }
  }

  float* hb = h + (size_t)b*CN_ + pix;
  #pragma unroll
  for (int o = 0; o < 8; ++o) {
    const int oc = ob + o;
    const float inv  = bn[oc] / sqrtf(bn[192+oc] + 1e-5f);
    const float beta = bn[64+oc] - bn[128+oc]*inv;
    float4 o4;
    o4.x = relu6f(fmaf(acc[o].x, inv, beta));
    o4.y = relu6f(fmaf(acc[o].y, inv, beta));
    o4.z = relu6f(fmaf(acc[o].z, inv, beta));
    o4.w = relu6f(fmaf(acc[o].w, inv, beta));
    *(float4*)(hb + (size_t)oc*N_) = o4;
  }
  if (half == 0) {
    const int m0 = wave*2;
    const float kb0 = kb[m0], kb1 = kb[m0+1];
    float* Kb = Kq + (size_t)b*MN_ + pix;
    float4 q0, q1;
    q0.x = softplusf(ak0.x+kb0); q0.y = softplusf(ak0.y+kb0);
    q0.z = softplusf(ak0.z+kb0); q0.w = softplusf(ak0.w+kb0);
    q1.x = softplusf(ak1.x+kb1); q1.y = softplusf(ak1.y+kb1);
    q1.z = softplusf(ak1.z+kb1); q1.w = softplusf(ak1.w+kb1);
    *(float4*)(Kb + (size_t)m0*N_)     = q0;
    *(float4*)(Kb + (size_t)(m0+1)*N_) = q1;
  }
}

// ---------------------------------------------------------------------------
// K2: s = relu6(bn1(dw5x5(h))) + relu6(bn2(dw3x3(h)))   32x32 tile per (b,c)
// ---------------------------------------------------------------------------
__global__ __launch_bounds__(256) void k_dw(const float* __restrict__ h,
                                            const float* __restrict__ w5,
                                            const float* __restrict__ w3,
                                            const float* __restrict__ bn1,
                                            const float* __restrict__ bn2,
                                            float* __restrict__ s)
{
  __shared__ float tile[36*37];
  const int tid = threadIdx.x;
  const int blk = blockIdx.x;              // B*C*49
  const int t   = blk % 49;
  const int bc  = blk / 49;
  const int c   = bc & 63;
  const int tx0 = (t % 7) * 32;
  const int ty0 = (t / 7) * 32;
  const float* hb = h + (size_t)bc * N_;

  for (int idx = tid; idx < 1296; idx += 256) {
    const int ly = idx / 36, lx = idx - ly*36;
    const int gy = ty0 + ly - 2, gx = tx0 + lx - 2;
    float v = 0.0f;
    if (gy >= 0 && gy < H_ && gx >= 0 && gx < W_) v = hb[gy*W_ + gx];
    tile[ly*37 + lx] = v;
  }
  __syncthreads();

  float w5r[25], w3r[9];
  #pragma unroll
  for (int i = 0; i < 25; ++i) w5r[i] = w5[c*25 + i];
  #pragma unroll
  for (int i = 0; i < 9; ++i)  w3r[i] = w3[c*9 + i];
  const float inv1 = bn1[c] / sqrtf(bn1[192+c] + 1e-5f);
  const float bet1 = bn1[64+c] - bn1[128+c]*inv1;
  const float inv2 = bn2[c] / sqrtf(bn2[192+c] + 1e-5f);
  const float bet2 = bn2[64+c] - bn2[128+c]*inv2;

  const int ty  = tid >> 3;
  const int tx4 = (tid & 7) << 2;
  float a5[4] = {0,0,0,0}, a3[4] = {0,0,0,0};
  #pragma unroll
  for (int dy = 0; dy < 5; ++dy) {
    float r[8];
    #pragma unroll
    for (int i = 0; i < 8; ++i) r[i] = tile[(ty+dy)*37 + tx4 + i];
    #pragma unroll
    for (int dx = 0; dx < 5; ++dx) {
      const float wv = w5r[dy*5+dx];
      #pragma unroll
      for (int p = 0; p < 4; ++p) a5[p] = fmaf(wv, r[p+dx], a5[p]);
    }
    if (dy >= 1 && dy <= 3) {
      #pragma unroll
      for (int dx = 1; dx <= 3; ++dx) {
        const float wv = w3r[(dy-1)*3+(dx-1)];
        #pragma unroll
        for (int p = 0; p < 4; ++p) a3[p] = fmaf(wv, r[p+dx], a3[p]);
      }
    }
  }
  float* sb = s + (size_t)bc * N_ + (ty0+ty)*W_ + tx0 + tx4;
  float4 o4;
  o4.x = relu6f(fmaf(a5[0],inv1,bet1)) + relu6f(fmaf(a3[0],inv2,bet2));
  o4.y = relu6f(fmaf(a5[1],inv1,bet1)) + relu6f(fmaf(a3[1],inv2,bet2));
  o4.z = relu6f(fmaf(a5[2],inv1,bet1)) + relu6f(fmaf(a3[2],inv2,bet2));
  o4.w = relu6f(fmaf(a5[3],inv1,bet1)) + relu6f(fmaf(a3[3],inv2,bet2));
  *(float4*)sb = o4;
}

// ---------------------------------------------------------------------------
// K3: V = conv1x1(x,v_w)+v_b + relu6(bn(conv1x1(s,fc2_w)))
// Thread = 4 px x 8 oc x 2 convs. Chunk-4 depth-2 pipeline: 8 KB/wave in
// flight (vs 2 KB round-4) -> latency hidden, VALU becomes the limiter.
// ---------------------------------------------------------------------------
__global__ __launch_bounds__(256, 3) void k_v(const float* __restrict__ x,
                                              const float* __restrict__ s,
                                              const float* __restrict__ vw,
                                              const float* __restrict__ vb,
                                              const float* __restrict__ fw,
                                              const float* __restrict__ fbn,
                                              float* __restrict__ V)
{
  __shared__ __align__(16) float wtv[64*32];  // [c][o']
  __shared__ __align__(16) float wtf[64*32];
  const int tid  = threadIdx.x;
  const int b    = blockIdx.x / 392;
  const int rem  = blockIdx.x % 392;
  const int pg   = rem >> 1;
  const int half = rem & 1;

  for (int idx = tid; idx < 2048; idx += 256) {
    const int c = idx >> 5, o = idx & 31;
    wtv[idx] = vw[(half*32 + o)*64 + c];
    wtf[idx] = fw[(half*32 + o)*64 + c];
  }
  __syncthreads();

  const int lane = tid & 63, wave = tid >> 6;
  const int pix = pg*256 + 4*lane;
  const float* xb = x + (size_t)b*CN_ + pix;
  const float* sb = s + (size_t)b*CN_ + pix;
  const int obl = wave*8;
  const int ob  = half*32 + obl;

  float4 av[8], af[8];
  #pragma unroll
  for (int i = 0; i < 8; ++i) { av[i] = make_float4(0,0,0,0); af[i] = make_float4(0,0,0,0); }

  float4 bx[2][4], bs2[2][4];
  #pragma unroll
  for (int j = 0; j < 4; ++j) {
    bx[0][j]  = *(const float4*)(xb + (size_t)j*N_);
    bs2[0][j] = *(const float4*)(sb + (size_t)j*N_);
  }

  #pragma unroll
  for (int ck = 0; ck < 16; ++ck) {
    const int cur = ck & 1, nxt = cur ^ 1;
    if (ck < 15) {
      #pragma unroll
      for (int j = 0; j < 4; ++j) {
        const size_t off = (size_t)((ck+1)*4 + j)*N_;
        bx[nxt][j]  = *(const float4*)(xb + off);
        bs2[nxt][j] = *(const float4*)(sb + off);
      }
    }
    #pragma unroll
    for (int j = 0; j < 4; ++j) {
      const int c = ck*4 + j;
      const float4 a0 = *(const float4*)&wtv[c*32 + obl];
      const float4 a1 = *(const float4*)&wtv[c*32 + obl + 4];
      const float4 f0 = *(const float4*)&wtf[c*32 + obl];
      const float4 f1 = *(const float4*)&wtf[c*32 + obl + 4];
      const float4 xv = bx[cur][j];
      const float4 sv = bs2[cur][j];
      const float wa[8] = {a0.x,a0.y,a0.z,a0.w,a1.x,a1.y,a1.z,a1.w};
      const float wf[8] = {f0.x,f0.y,f0.z,f0.w,f1.x,f1.y,f1.z,f1.w};
      #pragma unroll
      for (int o = 0; o < 8; ++o) {
        av[o].x = fmaf(wa[o], xv.x, av[o].x);
        av[o].y = fmaf(wa[o], xv.y, av[o].y);
        av[o].z = fmaf(wa[o], xv.z, av[o].z);
        av[o].w = fmaf(wa[o], xv.w, av[o].w);
        af[o].x = fmaf(wf[o], sv.x, af[o].x);
        af[o].y = fmaf(wf[o], sv.y, af[o].y);
        af[o].z = fmaf(wf[o], sv.z, af[o].z);
        af[o].w = fmaf(wf[o], sv.w, af[o].w);
      }
    }
  }

  float* Vb = V + (size_t)b*CN_ + pix;
  #pragma unroll
  for (int o = 0; o < 8; ++o) {
    const int oc = ob + o;
    const float inv  = fbn[oc] / sqrtf(fbn[192+oc] + 1e-5f);
    const float beta = fbn[64+oc] - fbn[128+oc]*inv;
    const float bias = vb[oc];
    float4 o4;
    o4.x = av[o].x + bias + relu6f(fmaf(af[o].x, inv, beta));
    o4.y = av[o].y + bias + relu6f(fmaf(af[o].y, inv, beta));
    o4.z = av[o].z + bias + relu6f(fmaf(af[o].z, inv, beta));
    o4.w = av[o].w + bias + relu6f(fmaf(af[o].w, inv, beta));
    *(float4*)(Vb + (size_t)oc*N_) = o4;
  }
}

// ---------------------------------------------------------------------------
// K4: KV[b,m,c] = sum_n K[b,m,n]*V[b,c,n];  Ksum[b,m] = sum_n K[b,m,n]
// ---------------------------------------------------------------------------
__global__ __launch_bounds__(256) void k_kv(const float* __restrict__ V,
                                            const float* __restrict__ Kq,
                                            float* __restrict__ KV,
                                            float* __restrict__ Ksum)
{
  const int blk = blockIdx.x;
  const int b   = blk >> 7;
  const int rem = blk & 127;
  const int cg  = rem >> 4;
  const int ch  = rem & 15;
  const int tid = threadIdx.x;
  const int base = ch * 3136;
  const int end  = base + 3136;
  const float* Kb = Kq + (size_t)b*MN_;
  const float* Vb = V  + (size_t)b*CN_ + (size_t)(cg*8)*N_;

  float acc[64];
  #pragma unroll
  for (int i = 0; i < 64; ++i) acc[i] = 0.0f;
  float ks[8] = {0,0,0,0,0,0,0,0};

  for (int n = base + tid; n < end; n += 256) {
    float kv[8];
    #pragma unroll
    for (int m2 = 0; m2 < 8; ++m2) kv[m2] = Kb[m2*N_ + n];
    #pragma unroll
    for (int m2 = 0; m2 < 8; ++m2) ks[m2] += kv[m2];
    #pragma unroll
    for (int c8 = 0; c8 < 8; ++c8) {
      const float vv = Vb[c8*N_ + n];
      #pragma unroll
      for (int m2 = 0; m2 < 8; ++m2)
        acc[m2*8+c8] = fmaf(kv[m2], vv, acc[m2*8+c8]);
    }
  }
  const int lane = tid & 63;
  float mine = 0.0f;
  #pragma unroll
  for (int jj = 0; jj < 64; ++jj) {
    float v = acc[jj];
    v += __shfl_xor(v, 1);
    v += __shfl_xor(v, 2);
    v += __shfl_xor(v, 4);
    v += __shfl_xor(v, 8);
    v += __shfl_xor(v, 16);
    v += __shfl_xor(v, 32);
    if (lane == jj) mine = v;
  }
  atomicAdd(&KV[b*512 + (lane>>3)*64 + cg*8 + (lane&7)], mine);
  if (cg == 0) {
    float mk = 0.0f;
    #pragma unroll
    for (int jj = 0; jj < 8; ++jj) {
      float v = ks[jj];
      v += __shfl_xor(v, 1);
      v += __shfl_xor(v, 2);
      v += __shfl_xor(v, 4);
      v += __shfl_xor(v, 8);
      v += __shfl_xor(v, 16);
      v += __shfl_xor(v, 32);
      if (lane == jj) mk = v;
    }
    if (lane < 8) atomicAdd(&Ksum[b*8 + lane], mk);
  }
}

// ---------------------------------------------------------------------------
// K5: Q on the fly; out = x + gamma * (Q^T KV) / (Q^T (Ksum+eps))
// x tile staged in LDS (64KB), 256 px / block.
// ---------------------------------------------------------------------------
__global__ __launch_bounds__(256) void k_out(const float* __restrict__ x,
                                             const float* __restrict__ qw,
                                             const float* __restrict__ qb,
                                             const float* __restrict__ gamma,
                                             const float* __restrict__ KV,
                                             const float* __restrict__ Ksum,
                                             float* __restrict__ out)
{
  __shared__ float xs[64*256];                 // xs[c][px]
  __shared__ __align__(16) float kvt[64*8];    // kvt[c][m]
  __shared__ __align__(16) float wqt[64*8];    // wqt[c][m]
  __shared__ float ksl[8];
  const int tid = threadIdx.x;
  const int b  = blockIdx.x / 196;
  const int pg = blockIdx.x % 196;
  const int pix0 = pg*256;
  const float* xb = x + (size_t)b*CN_ + pix0;

  for (int idx = tid; idx < 512; idx += 256) {
    const int m = idx >> 6, c = idx & 63;
    kvt[c*8 + m] = KV[b*512 + idx];
    wqt[c*8 + m] = qw[idx];
  }
  if (tid < 8) ksl[tid] = Ksum[b*8 + tid] + 1e-6f;
  for (int idx = tid; idx < 4096; idx += 256) {
    const int c = idx >> 6, i = idx & 63;
    const float4 v = ((const float4*)(xb + (size_t)c*N_))[i];
    ((float4*)&xs[c*256])[i] = v;
  }
  __syncthreads();

  float q[8] = {0,0,0,0,0,0,0,0};
  #pragma unroll 8
  for (int c = 0; c < 64; ++c) {
    const float xv = xs[c*256 + tid];
    const float4 w0 = *(const float4*)&wqt[c*8];
    const float4 w1 = *(const float4*)&wqt[c*8+4];
    q[0] = fmaf(w0.x, xv, q[0]);
    q[1] = fmaf(w0.y, xv, q[1]);
    q[2] = fmaf(w0.z, xv, q[2]);
    q[3] = fmaf(w0.w, xv, q[3]);
    q[4] = fmaf(w1.x, xv, q[4]);
    q[5] = fmaf(w1.y, xv, q[5]);
    q[6] = fmaf(w1.z, xv, q[6]);
    q[7] = fmaf(w1.w, xv, q[7]);
  }
  float den = 0.0f;
  #pragma unroll
  for (int m = 0; m < 8; ++m) {
    q[m] = softplusf(q[m] + qb[m]);
    den  = fmaf(q[m], ksl[m], den);
  }
  const float sc = gamma[0] / den;

  float* ob = out + (size_t)b*CN_ + pix0 + tid;
  #pragma unroll 8
  for (int c = 0; c < 64; ++c) {
    const float4 k0 = *(const float4*)&kvt[c*8];
    const float4 k1 = *(const float4*)&kvt[c*8+4];
    float wv;
    wv = q[0]*k0.x;
    wv = fmaf(q[1], k0.y, wv);
    wv = fmaf(q[2], k0.z, wv);
    wv = fmaf(q[3], k0.w, wv);
    wv = fmaf(q[4], k1.x, wv);
    wv = fmaf(q[5], k1.y, wv);
    wv = fmaf(q[6], k1.z, wv);
    wv = fmaf(q[7], k1.w, wv);
    ob[(size_t)c*N_] = fmaf(sc, wv, xs[c*256 + tid]);
  }
}

// ---------------------------------------------------------------------------
extern "C" void kernel_launch(void* const* d_in, const int* in_sizes, int n_in,
                              void* d_out, int out_size, void* d_ws, size_t ws_size,
                              hipStream_t stream) {
  const float* x      = (const float*)d_in[0];
  const float* gamma  = (const float*)d_in[1];
  const float* q_w    = (const float*)d_in[2];
  const float* q_b    = (const float*)d_in[3];
  const float* k_w    = (const float*)d_in[4];
  const float* k_b    = (const float*)d_in[5];
  const float* v_w    = (const float*)d_in[6];
  const float* v_b    = (const float*)d_in[7];
  const float* fc1_w  = (const float*)d_in[8];
  const float* fc1_bn = (const float*)d_in[9];
  const float* c1_w   = (const float*)d_in[10];
  const float* c1_bn  = (const float*)d_in[11];
  const float* c2_w   = (const float*)d_in[12];
  const float* c2_bn  = (const float*)d_in[13];
  const float* fc2_w  = (const float*)d_in[14];
  const float* fc2_bn = (const float*)d_in[15];
  float* outp = (float*)d_out;

  float* ws   = (float*)d_ws;
  float* bufA = ws;                        // h, later reused for V
  float* bufS = ws + (size_t)BCN_;
  float* bufK = ws + (size_t)2*BCN_;
  float* kv   = ws + (size_t)2*BCN_ + BMN_;
  float* ksum = kv + 2048;

  hipMemsetAsync(kv, 0, (2048 + 32)*sizeof(float), stream);

  k_fc1k<<<dim3(B_*392), dim3(256), 0, stream>>>(x, fc1_w, fc1_bn, k_w, k_b, bufA, bufK);
  k_dw  <<<dim3(B_*C_*49), dim3(256), 0, stream>>>(bufA, c1_w, c2_w, c1_bn, c2_bn, bufS);
  k_v   <<<dim3(B_*392), dim3(256), 0, stream>>>(x, bufS, v_w, v_b, fc2_w, fc2_bn, bufA);
  k_kv  <<<dim3(512), dim3(256), 0, stream>>>(bufA, bufK, kv, ksum);
  k_out <<<dim3(B_*196), dim3(256), 0, stream>>>(x, q_w, q_b, gamma, kv, ksum, outp);
}

// Round 6
// 592.305 us; speedup vs baseline: 1.4693x; 1.4693x over previous
//
#include <hip/hip_runtime.h>
#include <math.h>

#define B_ 4
#define C_ 64
#define M_ 8
#define H_ 224
#define W_ 224
#define N_ (H_*W_)        // 50176
#define CN_ (C_*N_)       // 3211264
#define MN_ (M_*N_)       // 401408
#define BCN_ (B_*CN_)
#define BMN_ (B_*MN_)

__device__ __forceinline__ float relu6f(float v){ return fminf(fmaxf(v,0.0f),6.0f); }
__device__ __forceinline__ float softplusf(float v){
  return v > 0.0f ? v + log1pf(expf(-v)) : log1pf(expf(v));
}

// a.{xyzw} += w * b.{xyzw}  — pure register ops, no arrays
#define FMA4(A, W, X) { A.x = fmaf((W), (X).x, A.x); A.y = fmaf((W), (X).y, A.y); \
                        A.z = fmaf((W), (X).z, A.z); A.w = fmaf((W), (X).w, A.w); }

// ---------------------------------------------------------------------------
// K1: h = relu6(bn(conv1x1(x, fc1_w)))  AND  K = softplus(conv1x1(x,k_w)+k_b)
// Thread = 4 px x 8 oc. Chunk-4 depth-2 pipeline with EXPLICIT SCALARS
// (round-5 lesson: indexed private arrays -> scratch -> 1 GB spill traffic).
// ---------------------------------------------------------------------------
__global__ __launch_bounds__(256) void k_fc1k(const float* __restrict__ x,
                                              const float* __restrict__ w,
                                              const float* __restrict__ bn,
                                              const float* __restrict__ kw,
                                              const float* __restrict__ kb,
                                              float* __restrict__ h,
                                              float* __restrict__ Kq)
{
  __shared__ __align__(16) float wt[64*32];   // wt[c][o']  o' = oc - half*32
  __shared__ __align__(16) float kt[64*8];    // kt[c][m]
  const int tid  = threadIdx.x;
  const int b    = blockIdx.x / 392;
  const int rem  = blockIdx.x % 392;
  const int pg   = rem >> 1;
  const int half = rem & 1;

  for (int idx = tid; idx < 2048; idx += 256) {
    const int c = idx >> 5, o = idx & 31;
    wt[idx] = w[(half*32 + o)*64 + c];
  }
  for (int idx = tid; idx < 512; idx += 256) {
    const int c = idx >> 3, m = idx & 7;
    kt[idx] = kw[m*64 + c];
  }
  __syncthreads();

  const int lane = tid & 63, wave = tid >> 6;
  const int pix = pg*256 + 4*lane;
  const float* xb = x + (size_t)b*CN_ + pix;
  const int obl = wave*8;
  const int ob  = half*32 + obl;

  float4 a0v = {0,0,0,0}, a1v = {0,0,0,0}, a2v = {0,0,0,0}, a3v = {0,0,0,0};
  float4 a4v = {0,0,0,0}, a5v = {0,0,0,0}, a6v = {0,0,0,0}, a7v = {0,0,0,0};
  float4 ak0 = {0,0,0,0}, ak1 = {0,0,0,0};

#define FC1_STEP(XV, CC) { \
    const float4 w0 = *(const float4*)&wt[(CC)*32 + obl]; \
    const float4 w1 = *(const float4*)&wt[(CC)*32 + obl + 4]; \
    FMA4(a0v, w0.x, XV); FMA4(a1v, w0.y, XV); FMA4(a2v, w0.z, XV); FMA4(a3v, w0.w, XV); \
    FMA4(a4v, w1.x, XV); FMA4(a5v, w1.y, XV); FMA4(a6v, w1.z, XV); FMA4(a7v, w1.w, XV); \
    if (half == 0) { \
      const float2 k2 = *(const float2*)&kt[(CC)*8 + wave*2]; \
      FMA4(ak0, k2.x, XV); FMA4(ak1, k2.y, XV); \
    } }

  float4 p0 = *(const float4*)(xb);
  float4 p1 = *(const float4*)(xb + (size_t)N_);
  float4 p2 = *(const float4*)(xb + (size_t)2*N_);
  float4 p3 = *(const float4*)(xb + (size_t)3*N_);
  #pragma unroll
  for (int ck = 0; ck < 16; ++ck) {
    const float4 c0 = p0, c1 = p1, c2 = p2, c3 = p3;
    if (ck < 15) {
      const float* nb = xb + (size_t)(ck+1)*4*N_;
      p0 = *(const float4*)(nb);
      p1 = *(const float4*)(nb + (size_t)N_);
      p2 = *(const float4*)(nb + (size_t)2*N_);
      p3 = *(const float4*)(nb + (size_t)3*N_);
    }
    FC1_STEP(c0, ck*4+0);
    FC1_STEP(c1, ck*4+1);
    FC1_STEP(c2, ck*4+2);
    FC1_STEP(c3, ck*4+3);
  }
#undef FC1_STEP

  float* hb = h + (size_t)b*CN_ + pix;
#define FC1_EPI(A, O) { \
    const int oc = ob + (O); \
    const float inv  = bn[oc] / sqrtf(bn[192+oc] + 1e-5f); \
    const float beta = bn[64+oc] - bn[128+oc]*inv; \
    float4 o4; \
    o4.x = relu6f(fmaf((A).x, inv, beta)); \
    o4.y = relu6f(fmaf((A).y, inv, beta)); \
    o4.z = relu6f(fmaf((A).z, inv, beta)); \
    o4.w = relu6f(fmaf((A).w, inv, beta)); \
    *(float4*)(hb + (size_t)oc*N_) = o4; }
  FC1_EPI(a0v,0) FC1_EPI(a1v,1) FC1_EPI(a2v,2) FC1_EPI(a3v,3)
  FC1_EPI(a4v,4) FC1_EPI(a5v,5) FC1_EPI(a6v,6) FC1_EPI(a7v,7)
#undef FC1_EPI

  if (half == 0) {
    const int m0 = wave*2;
    const float kb0 = kb[m0], kb1 = kb[m0+1];
    float* Kb = Kq + (size_t)b*MN_ + pix;
    float4 q0, q1;
    q0.x = softplusf(ak0.x+kb0); q0.y = softplusf(ak0.y+kb0);
    q0.z = softplusf(ak0.z+kb0); q0.w = softplusf(ak0.w+kb0);
    q1.x = softplusf(ak1.x+kb1); q1.y = softplusf(ak1.y+kb1);
    q1.z = softplusf(ak1.z+kb1); q1.w = softplusf(ak1.w+kb1);
    *(float4*)(Kb + (size_t)m0*N_)     = q0;
    *(float4*)(Kb + (size_t)(m0+1)*N_) = q1;
  }
}

// ---------------------------------------------------------------------------
// K2: s = relu6(bn1(dw5x5(h))) + relu6(bn2(dw3x3(h)))   32x32 tile per (b,c)
// ---------------------------------------------------------------------------
__global__ __launch_bounds__(256) void k_dw(const float* __restrict__ h,
                                            const float* __restrict__ w5,
                                            const float* __restrict__ w3,
                                            const float* __restrict__ bn1,
                                            const float* __restrict__ bn2,
                                            float* __restrict__ s)
{
  __shared__ float tile[36*37];
  const int tid = threadIdx.x;
  const int blk = blockIdx.x;              // B*C*49
  const int t   = blk % 49;
  const int bc  = blk / 49;
  const int c   = bc & 63;
  const int tx0 = (t % 7) * 32;
  const int ty0 = (t / 7) * 32;
  const float* hb = h + (size_t)bc * N_;

  for (int idx = tid; idx < 1296; idx += 256) {
    const int ly = idx / 36, lx = idx - ly*36;
    const int gy = ty0 + ly - 2, gx = tx0 + lx - 2;
    float v = 0.0f;
    if (gy >= 0 && gy < H_ && gx >= 0 && gx < W_) v = hb[gy*W_ + gx];
    tile[ly*37 + lx] = v;
  }
  __syncthreads();

  float w5r[25], w3r[9];
  #pragma unroll
  for (int i = 0; i < 25; ++i) w5r[i] = w5[c*25 + i];
  #pragma unroll
  for (int i = 0; i < 9; ++i)  w3r[i] = w3[c*9 + i];
  const float inv1 = bn1[c] / sqrtf(bn1[192+c] + 1e-5f);
  const float bet1 = bn1[64+c] - bn1[128+c]*inv1;
  const float inv2 = bn2[c] / sqrtf(bn2[192+c] + 1e-5f);
  const float bet2 = bn2[64+c] - bn2[128+c]*inv2;

  const int ty  = tid >> 3;
  const int tx4 = (tid & 7) << 2;
  float a5[4] = {0,0,0,0}, a3[4] = {0,0,0,0};
  #pragma unroll
  for (int dy = 0; dy < 5; ++dy) {
    float r[8];
    #pragma unroll
    for (int i = 0; i < 8; ++i) r[i] = tile[(ty+dy)*37 + tx4 + i];
    #pragma unroll
    for (int dx = 0; dx < 5; ++dx) {
      const float wv = w5r[dy*5+dx];
      #pragma unroll
      for (int p = 0; p < 4; ++p) a5[p] = fmaf(wv, r[p+dx], a5[p]);
    }
    if (dy >= 1 && dy <= 3) {
      #pragma unroll
      for (int dx = 1; dx <= 3; ++dx) {
        const float wv = w3r[(dy-1)*3+(dx-1)];
        #pragma unroll
        for (int p = 0; p < 4; ++p) a3[p] = fmaf(wv, r[p+dx], a3[p]);
      }
    }
  }
  float* sb = s + (size_t)bc * N_ + (ty0+ty)*W_ + tx0 + tx4;
  float4 o4;
  o4.x = relu6f(fmaf(a5[0],inv1,bet1)) + relu6f(fmaf(a3[0],inv2,bet2));
  o4.y = relu6f(fmaf(a5[1],inv1,bet1)) + relu6f(fmaf(a3[1],inv2,bet2));
  o4.z = relu6f(fmaf(a5[2],inv1,bet1)) + relu6f(fmaf(a3[2],inv2,bet2));
  o4.w = relu6f(fmaf(a5[3],inv1,bet1)) + relu6f(fmaf(a3[3],inv2,bet2));
  *(float4*)sb = o4;
}

// ---------------------------------------------------------------------------
// K3: V = conv1x1(x,v_w)+v_b + relu6(bn(conv1x1(s,fc2_w)))
// Thread = 4 px x 8 oc x 2 convs. Chunk-4 depth-2 pipeline, explicit scalars.
// ---------------------------------------------------------------------------
__global__ __launch_bounds__(256) void k_v(const float* __restrict__ x,
                                           const float* __restrict__ s,
                                           const float* __restrict__ vw,
                                           const float* __restrict__ vb,
                                           const float* __restrict__ fw,
                                           const float* __restrict__ fbn,
                                           float* __restrict__ V)
{
  __shared__ __align__(16) float wtv[64*32];  // [c][o']
  __shared__ __align__(16) float wtf[64*32];
  const int tid  = threadIdx.x;
  const int b    = blockIdx.x / 392;
  const int rem  = blockIdx.x % 392;
  const int pg   = rem >> 1;
  const int half = rem & 1;

  for (int idx = tid; idx < 2048; idx += 256) {
    const int c = idx >> 5, o = idx & 31;
    wtv[idx] = vw[(half*32 + o)*64 + c];
    wtf[idx] = fw[(half*32 + o)*64 + c];
  }
  __syncthreads();

  const int lane = tid & 63, wave = tid >> 6;
  const int pix = pg*256 + 4*lane;
  const float* xb = x + (size_t)b*CN_ + pix;
  const float* sb = s + (size_t)b*CN_ + pix;
  const int obl = wave*8;
  const int ob  = half*32 + obl;

  float4 av0={0,0,0,0},av1={0,0,0,0},av2={0,0,0,0},av3={0,0,0,0};
  float4 av4={0,0,0,0},av5={0,0,0,0},av6={0,0,0,0},av7={0,0,0,0};
  float4 af0={0,0,0,0},af1={0,0,0,0},af2={0,0,0,0},af3={0,0,0,0};
  float4 af4={0,0,0,0},af5={0,0,0,0},af6={0,0,0,0},af7={0,0,0,0};

#define V_STEP(XV, SV, CC) { \
    const float4 w0 = *(const float4*)&wtv[(CC)*32 + obl]; \
    const float4 w1 = *(const float4*)&wtv[(CC)*32 + obl + 4]; \
    const float4 g0 = *(const float4*)&wtf[(CC)*32 + obl]; \
    const float4 g1 = *(const float4*)&wtf[(CC)*32 + obl + 4]; \
    FMA4(av0, w0.x, XV); FMA4(av1, w0.y, XV); FMA4(av2, w0.z, XV); FMA4(av3, w0.w, XV); \
    FMA4(av4, w1.x, XV); FMA4(av5, w1.y, XV); FMA4(av6, w1.z, XV); FMA4(av7, w1.w, XV); \
    FMA4(af0, g0.x, SV); FMA4(af1, g0.y, SV); FMA4(af2, g0.z, SV); FMA4(af3, g0.w, SV); \
    FMA4(af4, g1.x, SV); FMA4(af5, g1.y, SV); FMA4(af6, g1.z, SV); FMA4(af7, g1.w, SV); }

  float4 px0 = *(const float4*)(xb);
  float4 px1 = *(const float4*)(xb + (size_t)N_);
  float4 px2 = *(const float4*)(xb + (size_t)2*N_);
  float4 px3 = *(const float4*)(xb + (size_t)3*N_);
  float4 ps0 = *(const float4*)(sb);
  float4 ps1 = *(const float4*)(sb + (size_t)N_);
  float4 ps2 = *(const float4*)(sb + (size_t)2*N_);
  float4 ps3 = *(const float4*)(sb + (size_t)3*N_);
  #pragma unroll
  for (int ck = 0; ck < 16; ++ck) {
    const float4 cx0 = px0, cx1 = px1, cx2 = px2, cx3 = px3;
    const float4 cs0 = ps0, cs1 = ps1, cs2 = ps2, cs3 = ps3;
    if (ck < 15) {
      const float* nx = xb + (size_t)(ck+1)*4*N_;
      const float* ns = sb + (size_t)(ck+1)*4*N_;
      px0 = *(const float4*)(nx);
      px1 = *(const float4*)(nx + (size_t)N_);
      px2 = *(const float4*)(nx + (size_t)2*N_);
      px3 = *(const float4*)(nx + (size_t)3*N_);
      ps0 = *(const float4*)(ns);
      ps1 = *(const float4*)(ns + (size_t)N_);
      ps2 = *(const float4*)(ns + (size_t)2*N_);
      ps3 = *(const float4*)(ns + (size_t)3*N_);
    }
    V_STEP(cx0, cs0, ck*4+0);
    V_STEP(cx1, cs1, ck*4+1);
    V_STEP(cx2, cs2, ck*4+2);
    V_STEP(cx3, cs3, ck*4+3);
  }
#undef V_STEP

  float* Vb = V + (size_t)b*CN_ + pix;
#define V_EPI(AV, AF, O) { \
    const int oc = ob + (O); \
    const float inv  = fbn[oc] / sqrtf(fbn[192+oc] + 1e-5f); \
    const float beta = fbn[64+oc] - fbn[128+oc]*inv; \
    const float bias = vb[oc]; \
    float4 o4; \
    o4.x = (AV).x + bias + relu6f(fmaf((AF).x, inv, beta)); \
    o4.y = (AV).y + bias + relu6f(fmaf((AF).y, inv, beta)); \
    o4.z = (AV).z + bias + relu6f(fmaf((AF).z, inv, beta)); \
    o4.w = (AV).w + bias + relu6f(fmaf((AF).w, inv, beta)); \
    *(float4*)(Vb + (size_t)oc*N_) = o4; }
  V_EPI(av0,af0,0) V_EPI(av1,af1,1) V_EPI(av2,af2,2) V_EPI(av3,af3,3)
  V_EPI(av4,af4,4) V_EPI(av5,af5,5) V_EPI(av6,af6,6) V_EPI(av7,af7,7)
#undef V_EPI
}

// ---------------------------------------------------------------------------
// K4: KV[b,m,c] = sum_n K[b,m,n]*V[b,c,n];  Ksum[b,m] = sum_n K[b,m,n]
// ---------------------------------------------------------------------------
__global__ __launch_bounds__(256) void k_kv(const float* __restrict__ V,
                                            const float* __restrict__ Kq,
                                            float* __restrict__ KV,
                                            float* __restrict__ Ksum)
{
  const int blk = blockIdx.x;
  const int b   = blk >> 7;
  const int rem = blk & 127;
  const int cg  = rem >> 4;
  const int ch  = rem & 15;
  const int tid = threadIdx.x;
  const int base = ch * 3136;
  const int end  = base + 3136;
  const float* Kb = Kq + (size_t)b*MN_;
  const float* Vb = V  + (size_t)b*CN_ + (size_t)(cg*8)*N_;

  float acc[64];
  #pragma unroll
  for (int i = 0; i < 64; ++i) acc[i] = 0.0f;
  float ks[8] = {0,0,0,0,0,0,0,0};

  for (int n = base + tid; n < end; n += 256) {
    float kv[8];
    #pragma unroll
    for (int m2 = 0; m2 < 8; ++m2) kv[m2] = Kb[m2*N_ + n];
    #pragma unroll
    for (int m2 = 0; m2 < 8; ++m2) ks[m2] += kv[m2];
    #pragma unroll
    for (int c8 = 0; c8 < 8; ++c8) {
      const float vv = Vb[c8*N_ + n];
      #pragma unroll
      for (int m2 = 0; m2 < 8; ++m2)
        acc[m2*8+c8] = fmaf(kv[m2], vv, acc[m2*8+c8]);
    }
  }
  const int lane = tid & 63;
  float mine = 0.0f;
  #pragma unroll
  for (int jj = 0; jj < 64; ++jj) {
    float v = acc[jj];
    v += __shfl_xor(v, 1);
    v += __shfl_xor(v, 2);
    v += __shfl_xor(v, 4);
    v += __shfl_xor(v, 8);
    v += __shfl_xor(v, 16);
    v += __shfl_xor(v, 32);
    if (lane == jj) mine = v;
  }
  atomicAdd(&KV[b*512 + (lane>>3)*64 + cg*8 + (lane&7)], mine);
  if (cg == 0) {
    float mk = 0.0f;
    #pragma unroll
    for (int jj = 0; jj < 8; ++jj) {
      float v = ks[jj];
      v += __shfl_xor(v, 1);
      v += __shfl_xor(v, 2);
      v += __shfl_xor(v, 4);
      v += __shfl_xor(v, 8);
      v += __shfl_xor(v, 16);
      v += __shfl_xor(v, 32);
      if (lane == jj) mk = v;
    }
    if (lane < 8) atomicAdd(&Ksum[b*8 + lane], mk);
  }
}

// ---------------------------------------------------------------------------
// K5: Q on the fly; out = x + gamma * (Q^T KV) / (Q^T (Ksum+eps))
// x tile staged in LDS (64KB), 256 px / block.
// ---------------------------------------------------------------------------
__global__ __launch_bounds__(256) void k_out(const float* __restrict__ x,
                                             const float* __restrict__ qw,
                                             const float* __restrict__ qb,
                                             const float* __restrict__ gamma,
                                             const float* __restrict__ KV,
                                             const float* __restrict__ Ksum,
                                             float* __restrict__ out)
{
  __shared__ float xs[64*256];                 // xs[c][px]
  __shared__ __align__(16) float kvt[64*8];    // kvt[c][m]
  __shared__ __align__(16) float wqt[64*8];    // wqt[c][m]
  __shared__ float ksl[8];
  const int tid = threadIdx.x;
  const int b  = blockIdx.x / 196;
  const int pg = blockIdx.x % 196;
  const int pix0 = pg*256;
  const float* xb = x + (size_t)b*CN_ + pix0;

  for (int idx = tid; idx < 512; idx += 256) {
    const int m = idx >> 6, c = idx & 63;
    kvt[c*8 + m] = KV[b*512 + idx];
    wqt[c*8 + m] = qw[idx];
  }
  if (tid < 8) ksl[tid] = Ksum[b*8 + tid] + 1e-6f;
  for (int idx = tid; idx < 4096; idx += 256) {
    const int c = idx >> 6, i = idx & 63;
    const float4 v = ((const float4*)(xb + (size_t)c*N_))[i];
    ((float4*)&xs[c*256])[i] = v;
  }
  __syncthreads();

  float q[8] = {0,0,0,0,0,0,0,0};
  #pragma unroll 8
  for (int c = 0; c < 64; ++c) {
    const float xv = xs[c*256 + tid];
    const float4 w0 = *(const float4*)&wqt[c*8];
    const float4 w1 = *(const float4*)&wqt[c*8+4];
    q[0] = fmaf(w0.x, xv, q[0]);
    q[1] = fmaf(w0.y, xv, q[1]);
    q[2] = fmaf(w0.z, xv, q[2]);
    q[3] = fmaf(w0.w, xv, q[3]);
    q[4] = fmaf(w1.x, xv, q[4]);
    q[5] = fmaf(w1.y, xv, q[5]);
    q[6] = fmaf(w1.z, xv, q[6]);
    q[7] = fmaf(w1.w, xv, q[7]);
  }
  float den = 0.0f;
  #pragma unroll
  for (int m = 0; m < 8; ++m) {
    q[m] = softplusf(q[m] + qb[m]);
    den  = fmaf(q[m], ksl[m], den);
  }
  const float sc = gamma[0] / den;

  float* ob = out + (size_t)b*CN_ + pix0 + tid;
  #pragma unroll 8
  for (int c = 0; c < 64; ++c) {
    const float4 k0 = *(const float4*)&kvt[c*8];
    const float4 k1 = *(const float4*)&kvt[c*8+4];
    float wv;
    wv = q[0]*k0.x;
    wv = fmaf(q[1], k0.y, wv);
    wv = fmaf(q[2], k0.z, wv);
    wv = fmaf(q[3], k0.w, wv);
    wv = fmaf(q[4], k1.x, wv);
    wv = fmaf(q[5], k1.y, wv);
    wv = fmaf(q[6], k1.z, wv);
    wv = fmaf(q[7], k1.w, wv);
    ob[(size_t)c*N_] = fmaf(sc, wv, xs[c*256 + tid]);
  }
}

// ---------------------------------------------------------------------------
extern "C" void kernel_launch(void* const* d_in, const int* in_sizes, int n_in,
                              void* d_out, int out_size, void* d_ws, size_t ws_size,
                              hipStream_t stream) {
  const float* x      = (const float*)d_in[0];
  const float* gamma  = (const float*)d_in[1];
  const float* q_w    = (const float*)d_in[2];
  const float* q_b    = (const float*)d_in[3];
  const float* k_w    = (const float*)d_in[4];
  const float* k_b    = (const float*)d_in[5];
  const float* v_w    = (const float*)d_in[6];
  const float* v_b    = (const float*)d_in[7];
  const float* fc1_w  = (const float*)d_in[8];
  const float* fc1_bn = (const float*)d_in[9];
  const float* c1_w   = (const float*)d_in[10];
  const float* c1_bn  = (const float*)d_in[11];
  const float* c2_w   = (const float*)d_in[12];
  const float* c2_bn  = (const float*)d_in[13];
  const float* fc2_w  = (const float*)d_in[14];
  const float* fc2_bn = (const float*)d_in[15];
  float* outp = (float*)d_out;

  float* ws   = (float*)d_ws;
  float* bufA = ws;                        // h, later reused for V
  float* bufS = ws + (size_t)BCN_;
  float* bufK = ws + (size_t)2*BCN_;
  float* kv   = ws + (size_t)2*BCN_ + BMN_;
  float* ksum = kv + 2048;

  hipMemsetAsync(kv, 0, (2048 + 32)*sizeof(float), stream);

  k_fc1k<<<dim3(B_*392), dim3(256), 0, stream>>>(x, fc1_w, fc1_bn, k_w, k_b, bufA, bufK);
  k_dw  <<<dim3(B_*C_*49), dim3(256), 0, stream>>>(bufA, c1_w, c2_w, c1_bn, c2_bn, bufS);
  k_v   <<<dim3(B_*392), dim3(256), 0, stream>>>(x, bufS, v_w, v_b, fc2_w, fc2_bn, bufA);
  k_kv  <<<dim3(512), dim3(256), 0, stream>>>(bufA, bufK, kv, ksum);
  k_out <<<dim3(B_*196), dim3(256), 0, stream>>>(x, q_w, q_b, gamma, kv, ksum, outp);
}

// Round 7
// 308.618 us; speedup vs baseline: 2.8200x; 1.9192x over previous
//
#include <hip/hip_runtime.h>
#include <math.h>

#define B_ 4
#define C_ 64
#define M_ 8
#define H_ 224
#define W_ 224
#define N_ (H_*W_)        // 50176
#define CN_ (C_*N_)       // 3211264
#define MN_ (M_*N_)       // 401408
#define BCN_ (B_*CN_)
#define BMN_ (B_*MN_)

__device__ __forceinline__ float relu6f(float v){ return fminf(fmaxf(v,0.0f),6.0f); }
__device__ __forceinline__ float softplusf(float v){
  return v > 0.0f ? v + log1pf(expf(-v)) : log1pf(expf(v));
}

#define FMA4(A, W, X) { A.x = fmaf((W), (X).x, A.x); A.y = fmaf((W), (X).y, A.y); \
                        A.z = fmaf((W), (X).z, A.z); A.w = fmaf((W), (X).w, A.w); }

// ---------------------------------------------------------------------------
// K1: h = relu6(bn(conv1x1(x))) AND K = softplus(conv1x1(x)+kb)
// 128-px tile, 64 oc/block. c in 8-wide slabs double-buffered in LDS
// (MLP lives in the block-wide staging, NOT per-thread VGPR prefetch —
// rounds 5/6 showed that path spills at VGPR=256).
// Thread = 4 px x 8 oc (och = 2*wave + lane/32) + 1 K-row (m = och).
// ---------------------------------------------------------------------------
__global__ __launch_bounds__(256) void k_fc1k(const float* __restrict__ x,
                                              const float* __restrict__ w,
                                              const float* __restrict__ bn,
                                              const float* __restrict__ kw,
                                              const float* __restrict__ kb,
                                              float* __restrict__ h,
                                              float* __restrict__ Kq)
{
  __shared__ float xsl[2*1024];   // [buf][c'(8)][px(128)]
  __shared__ float wl [2*512];    // [buf][c'(8)][oc(64)]
  __shared__ float kt [512];      // [c(64)][m(8)]
  const int tid  = threadIdx.x;
  const int b    = blockIdx.x / 392;
  const int pg   = blockIdx.x % 392;
  const int pix0 = pg*128;
  const float* xb = x + (size_t)b*CN_ + pix0;

  for (int idx = tid; idx < 512; idx += 256) {
    const int c = idx >> 3, m = idx & 7;
    kt[idx] = kw[m*64 + c];
  }

  // staging roles
  const int scp = tid >> 5;            // c' 0..7
  const int spx = (tid & 31) << 2;     // px 0,4,..,124
  const int e0 = tid*2, e1 = tid*2+1;
  const int wc0 = e0 >> 6, wo0 = e0 & 63;
  const int wc1 = e1 >> 6, wo1 = e1 & 63;

  { // stage slab 0
    const float4 xr = *(const float4*)(xb + (size_t)scp*N_ + spx);
    const float w0r = w[wo0*64 + wc0];
    const float w1r = w[wo1*64 + wc1];
    *(float4*)&xsl[scp*128 + spx] = xr;
    wl[e0] = w0r; wl[e1] = w1r;
  }
  __syncthreads();

  const int lane = tid & 63, wv_ = tid >> 6;
  const int och  = 2*wv_ + (lane >> 5);   // 0..7
  const int ocb  = och*8;
  const int px4  = (lane & 31) << 2;

  float4 ah[8];
  float4 ak = {0,0,0,0};
  #pragma unroll
  for (int i = 0; i < 8; ++i) ah[i] = make_float4(0.f,0.f,0.f,0.f);

  for (int ck = 0; ck < 8; ++ck) {
    const int cur = ck & 1, nxt = cur ^ 1;
    const float* xc = &xsl[cur*1024];
    const float* wc = &wl[cur*512];
    float4 xr; float w0r, w1r;
    if (ck < 7) {                       // issue next slab's global loads now
      const int c0n = (ck+1)*8;
      xr  = *(const float4*)(xb + (size_t)(c0n + scp)*N_ + spx);
      w0r = w[wo0*64 + c0n + wc0];
      w1r = w[wo1*64 + c0n + wc1];
    }
    #pragma unroll
    for (int cp = 0; cp < 8; ++cp) {
      const float4 xv = *(const float4*)&xc[cp*128 + px4];
      const float4 w0 = *(const float4*)&wc[cp*64 + ocb];
      const float4 w1 = *(const float4*)&wc[cp*64 + ocb + 4];
      const float kvw = kt[(ck*8+cp)*8 + och];
      FMA4(ah[0], w0.x, xv); FMA4(ah[1], w0.y, xv);
      FMA4(ah[2], w0.z, xv); FMA4(ah[3], w0.w, xv);
      FMA4(ah[4], w1.x, xv); FMA4(ah[5], w1.y, xv);
      FMA4(ah[6], w1.z, xv); FMA4(ah[7], w1.w, xv);
      FMA4(ak, kvw, xv);
    }
    if (ck < 7) {                       // park staged regs into next buffer
      *(float4*)&xsl[nxt*1024 + scp*128 + spx] = xr;
      wl[nxt*512 + e0] = w0r; wl[nxt*512 + e1] = w1r;
    }
    __syncthreads();
  }

  float* hb = h + (size_t)b*CN_ + pix0 + px4;
  #pragma unroll
  for (int o = 0; o < 8; ++o) {
    const int oc = ocb + o;
    const float inv  = bn[oc] / sqrtf(bn[192+oc] + 1e-5f);
    const float beta = bn[64+oc] - bn[128+oc]*inv;
    float4 o4;
    o4.x = relu6f(fmaf(ah[o].x, inv, beta));
    o4.y = relu6f(fmaf(ah[o].y, inv, beta));
    o4.z = relu6f(fmaf(ah[o].z, inv, beta));
    o4.w = relu6f(fmaf(ah[o].w, inv, beta));
    *(float4*)(hb + (size_t)oc*N_) = o4;
  }
  { // K row m = och
    const float kbm = kb[och];
    float4 q;
    q.x = softplusf(ak.x + kbm); q.y = softplusf(ak.y + kbm);
    q.z = softplusf(ak.z + kbm); q.w = softplusf(ak.w + kbm);
    *(float4*)(Kq + (size_t)b*MN_ + (size_t)och*N_ + pix0 + px4) = q;
  }
}

// ---------------------------------------------------------------------------
// K2: s = relu6(bn1(dw5x5(h))) + relu6(bn2(dw3x3(h)))   32x32 tile per (b,c)
// ---------------------------------------------------------------------------
__global__ __launch_bounds__(256) void k_dw(const float* __restrict__ h,
                                            const float* __restrict__ w5,
                                            const float* __restrict__ w3,
                                            const float* __restrict__ bn1,
                                            const float* __restrict__ bn2,
                                            float* __restrict__ s)
{
  __shared__ float tile[36*37];
  const int tid = threadIdx.x;
  const int blk = blockIdx.x;              // B*C*49
  const int t   = blk % 49;
  const int bc  = blk / 49;
  const int c   = bc & 63;
  const int tx0 = (t % 7) * 32;
  const int ty0 = (t / 7) * 32;
  const float* hb = h + (size_t)bc * N_;

  for (int idx = tid; idx < 1296; idx += 256) {
    const int ly = idx / 36, lx = idx - ly*36;
    const int gy = ty0 + ly - 2, gx = tx0 + lx - 2;
    float v = 0.0f;
    if (gy >= 0 && gy < H_ && gx >= 0 && gx < W_) v = hb[gy*W_ + gx];
    tile[ly*37 + lx] = v;
  }
  __syncthreads();

  float w5r[25], w3r[9];
  #pragma unroll
  for (int i = 0; i < 25; ++i) w5r[i] = w5[c*25 + i];
  #pragma unroll
  for (int i = 0; i < 9; ++i)  w3r[i] = w3[c*9 + i];
  const float inv1 = bn1[c] / sqrtf(bn1[192+c] + 1e-5f);
  const float bet1 = bn1[64+c] - bn1[128+c]*inv1;
  const float inv2 = bn2[c] / sqrtf(bn2[192+c] + 1e-5f);
  const float bet2 = bn2[64+c] - bn2[128+c]*inv2;

  const int ty  = tid >> 3;
  const int tx4 = (tid & 7) << 2;
  float a5[4] = {0,0,0,0}, a3[4] = {0,0,0,0};
  #pragma unroll
  for (int dy = 0; dy < 5; ++dy) {
    float r[8];
    #pragma unroll
    for (int i = 0; i < 8; ++i) r[i] = tile[(ty+dy)*37 + tx4 + i];
    #pragma unroll
    for (int dx = 0; dx < 5; ++dx) {
      const float wv = w5r[dy*5+dx];
      #pragma unroll
      for (int p = 0; p < 4; ++p) a5[p] = fmaf(wv, r[p+dx], a5[p]);
    }
    if (dy >= 1 && dy <= 3) {
      #pragma unroll
      for (int dx = 1; dx <= 3; ++dx) {
        const float wv = w3r[(dy-1)*3+(dx-1)];
        #pragma unroll
        for (int p = 0; p < 4; ++p) a3[p] = fmaf(wv, r[p+dx], a3[p]);
      }
    }
  }
  float* sb = s + (size_t)bc * N_ + (ty0+ty)*W_ + tx0 + tx4;
  float4 o4;
  o4.x = relu6f(fmaf(a5[0],inv1,bet1)) + relu6f(fmaf(a3[0],inv2,bet2));
  o4.y = relu6f(fmaf(a5[1],inv1,bet1)) + relu6f(fmaf(a3[1],inv2,bet2));
  o4.z = relu6f(fmaf(a5[2],inv1,bet1)) + relu6f(fmaf(a3[2],inv2,bet2));
  o4.w = relu6f(fmaf(a5[3],inv1,bet1)) + relu6f(fmaf(a3[3],inv2,bet2));
  *(float4*)sb = o4;
}

// ---------------------------------------------------------------------------
// K3: V = conv1x1(x,v_w)+v_b + relu6(bn(conv1x1(s,fc2_w)))
// Same LDS-slab pipeline as K1; two data streams (x,s), two weight slabs.
// ---------------------------------------------------------------------------
__global__ __launch_bounds__(256) void k_v(const float* __restrict__ x,
                                           const float* __restrict__ s,
                                           const float* __restrict__ vw,
                                           const float* __restrict__ vb,
                                           const float* __restrict__ fw,
                                           const float* __restrict__ fbn,
                                           float* __restrict__ V)
{
  __shared__ float xsl[2*1024];
  __shared__ float ssl[2*1024];
  __shared__ float wvl[2*512];
  __shared__ float wfl[2*512];
  const int tid  = threadIdx.x;
  const int b    = blockIdx.x / 392;
  const int pg   = blockIdx.x % 392;
  const int pix0 = pg*128;
  const float* xb = x + (size_t)b*CN_ + pix0;
  const float* sb = s + (size_t)b*CN_ + pix0;

  const int scp = tid >> 5;
  const int spx = (tid & 31) << 2;
  const int e0 = tid*2, e1 = tid*2+1;
  const int wc0 = e0 >> 6, wo0 = e0 & 63;
  const int wc1 = e1 >> 6, wo1 = e1 & 63;

  { // stage slab 0
    const float4 xr = *(const float4*)(xb + (size_t)scp*N_ + spx);
    const float4 sr = *(const float4*)(sb + (size_t)scp*N_ + spx);
    const float a0 = vw[wo0*64 + wc0], a1 = vw[wo1*64 + wc1];
    const float f0 = fw[wo0*64 + wc0], f1 = fw[wo1*64 + wc1];
    *(float4*)&xsl[scp*128 + spx] = xr;
    *(float4*)&ssl[scp*128 + spx] = sr;
    wvl[e0] = a0; wvl[e1] = a1;
    wfl[e0] = f0; wfl[e1] = f1;
  }
  __syncthreads();

  const int lane = tid & 63, wv_ = tid >> 6;
  const int och  = 2*wv_ + (lane >> 5);
  const int ocb  = och*8;
  const int px4  = (lane & 31) << 2;

  float4 av[8], af[8];
  #pragma unroll
  for (int i = 0; i < 8; ++i) { av[i] = make_float4(0,0,0,0); af[i] = make_float4(0,0,0,0); }

  for (int ck = 0; ck < 8; ++ck) {
    const int cur = ck & 1, nxt = cur ^ 1;
    const float* xc = &xsl[cur*1024];
    const float* sc2 = &ssl[cur*1024];
    const float* wvc = &wvl[cur*512];
    const float* wfc = &wfl[cur*512];
    float4 xr, sr; float a0r, a1r, f0r, f1r;
    if (ck < 7) {
      const int c0n = (ck+1)*8;
      xr  = *(const float4*)(xb + (size_t)(c0n + scp)*N_ + spx);
      sr  = *(const float4*)(sb + (size_t)(c0n + scp)*N_ + spx);
      a0r = vw[wo0*64 + c0n + wc0]; a1r = vw[wo1*64 + c0n + wc1];
      f0r = fw[wo0*64 + c0n + wc0]; f1r = fw[wo1*64 + c0n + wc1];
    }
    #pragma unroll
    for (int cp = 0; cp < 8; ++cp) {
      const float4 xv = *(const float4*)&xc[cp*128 + px4];
      const float4 sv = *(const float4*)&sc2[cp*128 + px4];
      const float4 wa0 = *(const float4*)&wvc[cp*64 + ocb];
      const float4 wa1 = *(const float4*)&wvc[cp*64 + ocb + 4];
      const float4 wf0 = *(const float4*)&wfc[cp*64 + ocb];
      const float4 wf1 = *(const float4*)&wfc[cp*64 + ocb + 4];
      FMA4(av[0], wa0.x, xv); FMA4(av[1], wa0.y, xv);
      FMA4(av[2], wa0.z, xv); FMA4(av[3], wa0.w, xv);
      FMA4(av[4], wa1.x, xv); FMA4(av[5], wa1.y, xv);
      FMA4(av[6], wa1.z, xv); FMA4(av[7], wa1.w, xv);
      FMA4(af[0], wf0.x, sv); FMA4(af[1], wf0.y, sv);
      FMA4(af[2], wf0.z, sv); FMA4(af[3], wf0.w, sv);
      FMA4(af[4], wf1.x, sv); FMA4(af[5], wf1.y, sv);
      FMA4(af[6], wf1.z, sv); FMA4(af[7], wf1.w, sv);
    }
    if (ck < 7) {
      *(float4*)&xsl[nxt*1024 + scp*128 + spx] = xr;
      *(float4*)&ssl[nxt*1024 + scp*128 + spx] = sr;
      wvl[nxt*512 + e0] = a0r; wvl[nxt*512 + e1] = a1r;
      wfl[nxt*512 + e0] = f0r; wfl[nxt*512 + e1] = f1r;
    }
    __syncthreads();
  }

  float* Vb = V + (size_t)b*CN_ + pix0 + px4;
  #pragma unroll
  for (int o = 0; o < 8; ++o) {
    const int oc = ocb + o;
    const float inv  = fbn[oc] / sqrtf(fbn[192+oc] + 1e-5f);
    const float beta = fbn[64+oc] - fbn[128+oc]*inv;
    const float bias = vb[oc];
    float4 o4;
    o4.x = av[o].x + bias + relu6f(fmaf(af[o].x, inv, beta));
    o4.y = av[o].y + bias + relu6f(fmaf(af[o].y, inv, beta));
    o4.z = av[o].z + bias + relu6f(fmaf(af[o].z, inv, beta));
    o4.w = av[o].w + bias + relu6f(fmaf(af[o].w, inv, beta));
    *(float4*)(Vb + (size_t)oc*N_) = o4;
  }
}

// ---------------------------------------------------------------------------
// K4: KV[b,m,c] = sum_n K[b,m,n]*V[b,c,n];  Ksum[b,m] = sum_n K[b,m,n]
// ---------------------------------------------------------------------------
__global__ __launch_bounds__(256) void k_kv(const float* __restrict__ V,
                                            const float* __restrict__ Kq,
                                            float* __restrict__ KV,
                                            float* __restrict__ Ksum)
{
  const int blk = blockIdx.x;
  const int b   = blk >> 7;
  const int rem = blk & 127;
  const int cg  = rem >> 4;
  const int ch  = rem & 15;
  const int tid = threadIdx.x;
  const int base = ch * 3136;
  const int end  = base + 3136;
  const float* Kb = Kq + (size_t)b*MN_;
  const float* Vb = V  + (size_t)b*CN_ + (size_t)(cg*8)*N_;

  float acc[64];
  #pragma unroll
  for (int i = 0; i < 64; ++i) acc[i] = 0.0f;
  float ks[8] = {0,0,0,0,0,0,0,0};

  for (int n = base + tid; n < end; n += 256) {
    float kv[8];
    #pragma unroll
    for (int m2 = 0; m2 < 8; ++m2) kv[m2] = Kb[m2*N_ + n];
    #pragma unroll
    for (int m2 = 0; m2 < 8; ++m2) ks[m2] += kv[m2];
    #pragma unroll
    for (int c8 = 0; c8 < 8; ++c8) {
      const float vv = Vb[c8*N_ + n];
      #pragma unroll
      for (int m2 = 0; m2 < 8; ++m2)
        acc[m2*8+c8] = fmaf(kv[m2], vv, acc[m2*8+c8]);
    }
  }
  const int lane = tid & 63;
  float mine = 0.0f;
  #pragma unroll
  for (int jj = 0; jj < 64; ++jj) {
    float v = acc[jj];
    v += __shfl_xor(v, 1);
    v += __shfl_xor(v, 2);
    v += __shfl_xor(v, 4);
    v += __shfl_xor(v, 8);
    v += __shfl_xor(v, 16);
    v += __shfl_xor(v, 32);
    if (lane == jj) mine = v;
  }
  atomicAdd(&KV[b*512 + (lane>>3)*64 + cg*8 + (lane&7)], mine);
  if (cg == 0) {
    float mk = 0.0f;
    #pragma unroll
    for (int jj = 0; jj < 8; ++jj) {
      float v = ks[jj];
      v += __shfl_xor(v, 1);
      v += __shfl_xor(v, 2);
      v += __shfl_xor(v, 4);
      v += __shfl_xor(v, 8);
      v += __shfl_xor(v, 16);
      v += __shfl_xor(v, 32);
      if (lane == jj) mk = v;
    }
    if (lane < 8) atomicAdd(&Ksum[b*8 + lane], mk);
  }
}

// ---------------------------------------------------------------------------
// K5: Q on the fly; out = x + gamma * (Q^T KV) / (Q^T (Ksum+eps))
// x tile staged in LDS (64KB), 256 px / block.
// ---------------------------------------------------------------------------
__global__ __launch_bounds__(256) void k_out(const float* __restrict__ x,
                                             const float* __restrict__ qw,
                                             const float* __restrict__ qb,
                                             const float* __restrict__ gamma,
                                             const float* __restrict__ KV,
                                             const float* __restrict__ Ksum,
                                             float* __restrict__ out)
{
  __shared__ float xs[64*256];                 // xs[c][px]
  __shared__ __align__(16) float kvt[64*8];    // kvt[c][m]
  __shared__ __align__(16) float wqt[64*8];    // wqt[c][m]
  __shared__ float ksl[8];
  const int tid = threadIdx.x;
  const int b  = blockIdx.x / 196;
  const int pg = blockIdx.x % 196;
  const int pix0 = pg*256;
  const float* xb = x + (size_t)b*CN_ + pix0;

  for (int idx = tid; idx < 512; idx += 256) {
    const int m = idx >> 6, c = idx & 63;
    kvt[c*8 + m] = KV[b*512 + idx];
    wqt[c*8 + m] = qw[idx];
  }
  if (tid < 8) ksl[tid] = Ksum[b*8 + tid] + 1e-6f;
  for (int idx = tid; idx < 4096; idx += 256) {
    const int c = idx >> 6, i = idx & 63;
    const float4 v = ((const float4*)(xb + (size_t)c*N_))[i];
    ((float4*)&xs[c*256])[i] = v;
  }
  __syncthreads();

  float q[8] = {0,0,0,0,0,0,0,0};
  #pragma unroll 8
  for (int c = 0; c < 64; ++c) {
    const float xv = xs[c*256 + tid];
    const float4 w0 = *(const float4*)&wqt[c*8];
    const float4 w1 = *(const float4*)&wqt[c*8+4];
    q[0] = fmaf(w0.x, xv, q[0]);
    q[1] = fmaf(w0.y, xv, q[1]);
    q[2] = fmaf(w0.z, xv, q[2]);
    q[3] = fmaf(w0.w, xv, q[3]);
    q[4] = fmaf(w1.x, xv, q[4]);
    q[5] = fmaf(w1.y, xv, q[5]);
    q[6] = fmaf(w1.z, xv, q[6]);
    q[7] = fmaf(w1.w, xv, q[7]);
  }
  float den = 0.0f;
  #pragma unroll
  for (int m = 0; m < 8; ++m) {
    q[m] = softplusf(q[m] + qb[m]);
    den  = fmaf(q[m], ksl[m], den);
  }
  const float sc = gamma[0] / den;

  float* ob = out + (size_t)b*CN_ + pix0 + tid;
  #pragma unroll 8
  for (int c = 0; c < 64; ++c) {
    const float4 k0 = *(const float4*)&kvt[c*8];
    const float4 k1 = *(const float4*)&kvt[c*8+4];
    float wv;
    wv = q[0]*k0.x;
    wv = fmaf(q[1], k0.y, wv);
    wv = fmaf(q[2], k0.z, wv);
    wv = fmaf(q[3], k0.w, wv);
    wv = fmaf(q[4], k1.x, wv);
    wv = fmaf(q[5], k1.y, wv);
    wv = fmaf(q[6], k1.z, wv);
    wv = fmaf(q[7], k1.w, wv);
    ob[(size_t)c*N_] = fmaf(sc, wv, xs[c*256 + tid]);
  }
}

// ---------------------------------------------------------------------------
extern "C" void kernel_launch(void* const* d_in, const int* in_sizes, int n_in,
                              void* d_out, int out_size, void* d_ws, size_t ws_size,
                              hipStream_t stream) {
  const float* x      = (const float*)d_in[0];
  const float* gamma  = (const float*)d_in[1];
  const float* q_w    = (const float*)d_in[2];
  const float* q_b    = (const float*)d_in[3];
  const float* k_w    = (const float*)d_in[4];
  const float* k_b    = (const float*)d_in[5];
  const float* v_w    = (const float*)d_in[6];
  const float* v_b    = (const float*)d_in[7];
  const float* fc1_w  = (const float*)d_in[8];
  const float* fc1_bn = (const float*)d_in[9];
  const float* c1_w   = (const float*)d_in[10];
  const float* c1_bn  = (const float*)d_in[11];
  const float* c2_w   = (const float*)d_in[12];
  const float* c2_bn  = (const float*)d_in[13];
  const float* fc2_w  = (const float*)d_in[14];
  const float* fc2_bn = (const float*)d_in[15];
  float* outp = (float*)d_out;

  float* ws   = (float*)d_ws;
  float* bufA = ws;                        // h, later reused for V
  float* bufS = ws + (size_t)BCN_;
  float* bufK = ws + (size_t)2*BCN_;
  float* kv   = ws + (size_t)2*BCN_ + BMN_;
  float* ksum = kv + 2048;

  hipMemsetAsync(kv, 0, (2048 + 32)*sizeof(float), stream);

  k_fc1k<<<dim3(B_*392), dim3(256), 0, stream>>>(x, fc1_w, fc1_bn, k_w, k_b, bufA, bufK);
  k_dw  <<<dim3(B_*C_*49), dim3(256), 0, stream>>>(bufA, c1_w, c2_w, c1_bn, c2_bn, bufS);
  k_v   <<<dim3(B_*392), dim3(256), 0, stream>>>(x, bufS, v_w, v_b, fc2_w, fc2_bn, bufA);
  k_kv  <<<dim3(512), dim3(256), 0, stream>>>(bufA, bufK, kv, ksum);
  k_out <<<dim3(B_*196), dim3(256), 0, stream>>>(x, q_w, q_b, gamma, kv, ksum, outp);
}